// Round 8
// baseline (231.606 us; speedup 1.0000x reference)
//
#include <hip/hip_runtime.h>
#include <math.h>

#define NFD 128   // node features
#define EF_ 16    // edge features
#define EFIL 32   // edge MLP hidden
#define NFIL 64   // GCN layer-1 out
#define CLS 16    // classes

typedef unsigned int uint;
typedef unsigned long long ull;
typedef unsigned short ushort;

__device__ inline void fma4(float4& a, float s, const float4& w) {
  a.x = fmaf(s, w.x, a.x); a.y = fmaf(s, w.y, a.y);
  a.z = fmaf(s, w.z, a.z); a.w = fmaf(s, w.w, a.w);
}

// round-to-nearest-even bf16 bits of a finite float
__device__ inline uint bf16_rn(float f) {
  uint u = __float_as_uint(f);
  return (u + 0x7FFFu + ((u >> 16) & 1u)) >> 16;
}
__device__ inline float entw(uint lo) {          // decode (ew15<<17) -> float
  return __uint_as_float((lo >> 17) << 16);
}

// k1: edge MLP -> sigmoid weight; linked-list push into one of 4 replicated,
// 32B-strided heads: old = atomicExch(&head[tgt*8 + rep], e);
// payload store is coalesced (e-indexed).
__global__ __launch_bounds__(256) void edge_mlp_link_kernel(
    const float* __restrict__ edge_x, const int* __restrict__ ei,
    const float* __restrict__ W1, const float* __restrict__ b1,
    const float* __restrict__ W2, const float* __restrict__ b2,
    int* __restrict__ head, ull* __restrict__ nextbuf, int E) {
  __shared__ __align__(16) float sW1[EF_ * EFIL];  // [k][j] 16x32
  __shared__ float sb1[EFIL];
  __shared__ float sW2[EFIL];
  __shared__ float sb2v;
  int t = threadIdx.x;
  for (int idx = t; idx < EF_ * EFIL / 4; idx += 256)
    reinterpret_cast<float4*>(sW1)[idx] = reinterpret_cast<const float4*>(W1)[idx];
  if (t < EFIL) { sb1[t] = b1[t]; sW2[t] = W2[t]; }
  if (t == 64) sb2v = b2[0];
  __syncthreads();
  int e = blockIdx.x * 256 + t;
  if (e >= E) return;
  const float4* ex4 = reinterpret_cast<const float4*>(edge_x) + (size_t)e * (EF_ / 4);
  float ex[EF_];
  #pragma unroll
  for (int q = 0; q < EF_ / 4; q++) {
    float4 v = ex4[q];
    ex[4*q+0] = v.x; ex[4*q+1] = v.y; ex[4*q+2] = v.z; ex[4*q+3] = v.w;
  }
  float acc[EFIL];
  #pragma unroll
  for (int j = 0; j < EFIL; j++) acc[j] = sb1[j];
  #pragma unroll
  for (int k = 0; k < EF_; k++) {
    float xk = ex[k];
    #pragma unroll
    for (int j4 = 0; j4 < EFIL / 4; j4++) {
      float4 w = reinterpret_cast<const float4*>(sW1)[k * (EFIL/4) + j4];
      acc[4*j4+0] = fmaf(xk, w.x, acc[4*j4+0]);
      acc[4*j4+1] = fmaf(xk, w.y, acc[4*j4+1]);
      acc[4*j4+2] = fmaf(xk, w.z, acc[4*j4+2]);
      acc[4*j4+3] = fmaf(xk, w.w, acc[4*j4+3]);
    }
  }
  float s = sb2v;
  #pragma unroll
  for (int j = 0; j < EFIL; j++) s = fmaf(fmaxf(acc[j], 0.f), sW2[j], s);
  float sig = 1.0f / (1.0f + __expf(-s));
  int sv = ei[e], tg = ei[(size_t)E + e];
  uint lo = ((bf16_rn(sig) & 0x7FFFu) << 17) | (uint)sv;
  int old = atomicExch(&head[(size_t)tg * 8 + (blockIdx.x & 3)], e);
  nextbuf[e] = ((ull)(uint)old << 32) | lo;
}

// k2: walk the 4 replica chains per node (interleaved -> 4 loads in flight),
// store entries COLUMN-MAJOR: slot[p*n + i] (wave-coalesced stores),
// per-node count + dinv = rsqrt(1 + sum ew). 1 thread per node.
__global__ __launch_bounds__(256) void walk_kernel(
    const int* __restrict__ head, const ull* __restrict__ nextbuf,
    uint* __restrict__ slotc, int* __restrict__ grp_cnt,
    float* __restrict__ dinv, int caprows, int n) {
  int i = blockIdx.x * blockDim.x + threadIdx.x;
  if (i >= n) return;
  int4 h = *reinterpret_cast<const int4*>(head + (size_t)i * 8);
  int e0 = h.x, e1 = h.y, e2 = h.z, e3 = h.w;
  int cnt = 0;
  float sum = 0.f;
  while (e0 >= 0 || e1 >= 0 || e2 >= 0 || e3 >= 0) {
    ull v0 = 0, v1 = 0, v2 = 0, v3 = 0;
    if (e0 >= 0) v0 = nextbuf[e0];
    if (e1 >= 0) v1 = nextbuf[e1];
    if (e2 >= 0) v2 = nextbuf[e2];
    if (e3 >= 0) v3 = nextbuf[e3];
    if (e0 >= 0) { uint lo = (uint)v0; sum += entw(lo);
      if (cnt < caprows) slotc[(size_t)cnt * n + i] = lo;
      cnt++; e0 = (int)(uint)(v0 >> 32); }
    if (e1 >= 0) { uint lo = (uint)v1; sum += entw(lo);
      if (cnt < caprows) slotc[(size_t)cnt * n + i] = lo;
      cnt++; e1 = (int)(uint)(v1 >> 32); }
    if (e2 >= 0) { uint lo = (uint)v2; sum += entw(lo);
      if (cnt < caprows) slotc[(size_t)cnt * n + i] = lo;
      cnt++; e2 = (int)(uint)(v2 >> 32); }
    if (e3 >= 0) { uint lo = (uint)v3; sum += entw(lo);
      if (cnt < caprows) slotc[(size_t)cnt * n + i] = lo;
      cnt++; e3 = (int)(uint)(v3 >> 32); }
  }
  grp_cnt[i] = min(cnt, caprows);
  dinv[i] = rsqrtf(1.0f + sum);
}

// k3: xw = x @ Wc1, output bf16 (packed 2/uint, row = 32 uints)
__global__ __launch_bounds__(256) void gemm1_kernel(
    const float* __restrict__ x, const float* __restrict__ Wc1,
    uint* __restrict__ xwb, int n) {
  __shared__ __align__(16) float sW[NFD * NFIL];  // 32 KB, [k][c]
  int t = threadIdx.x;
  for (int idx = t; idx < NFD * NFIL / 4; idx += 256)
    reinterpret_cast<float4*>(sW)[idx] = reinterpret_cast<const float4*>(Wc1)[idx];
  __syncthreads();
  int tc = t & 15;
  int tr = t >> 4;
  int nrb = (n + 31) >> 5;
  const float4* sW4 = reinterpret_cast<const float4*>(sW);
  for (int rb = blockIdx.x; rb < nrb; rb += gridDim.x) {
    int r0 = rb * 32 + tr * 2;
    int r1 = r0 + 1;
    int c0 = r0 < n ? r0 : n - 1;
    int c1 = r1 < n ? r1 : n - 1;
    const float4* xr0 = reinterpret_cast<const float4*>(x + (size_t)c0 * NFD);
    const float4* xr1 = reinterpret_cast<const float4*>(x + (size_t)c1 * NFD);
    float4 a0 = {0, 0, 0, 0}, a1 = {0, 0, 0, 0};
    #pragma unroll 4
    for (int k4 = 0; k4 < NFD / 4; k4++) {
      float4 xa = xr0[k4];
      float4 xb = xr1[k4];
      float4 w0 = sW4[(k4*4+0)*16 + tc];
      float4 w1 = sW4[(k4*4+1)*16 + tc];
      float4 w2 = sW4[(k4*4+2)*16 + tc];
      float4 w3 = sW4[(k4*4+3)*16 + tc];
      fma4(a0, xa.x, w0); fma4(a0, xa.y, w1); fma4(a0, xa.z, w2); fma4(a0, xa.w, w3);
      fma4(a1, xb.x, w0); fma4(a1, xb.y, w1); fma4(a1, xb.z, w2); fma4(a1, xb.w, w3);
    }
    if (r0 < n) {
      uint2 o = {bf16_rn(a0.x) | (bf16_rn(a0.y) << 16),
                 bf16_rn(a0.z) | (bf16_rn(a0.w) << 16)};
      reinterpret_cast<uint2*>(xwb + (size_t)r0 * 32)[tc] = o;
    }
    if (r1 < n) {
      uint2 o = {bf16_rn(a1.x) | (bf16_rn(a1.y) << 16),
                 bf16_rn(a1.z) | (bf16_rn(a1.w) << 16)};
      reinterpret_cast<uint2*>(xwb + (size_t)r1 * 32)[tc] = o;
    }
  }
}

// k4: agg layer 1 (register acc, 16 lanes/node) + fused relu/bias + @Wc2 -> yw (bf16)
__global__ __launch_bounds__(256) void agg1_fused_kernel(
    const int* __restrict__ grp_cnt, const uint* __restrict__ slotc,
    const float* __restrict__ dinv, const uint* __restrict__ xwb,
    const float* __restrict__ bc1, const float* __restrict__ Wc2,
    ushort* __restrict__ ywb, int n) {
  __shared__ float sh[16][NFIL + 4];   // 4.4 KB
  __shared__ float sW2[NFIL * CLS];    // 4 KB
  __shared__ float sb1[NFIL];
  int t = threadIdx.x;
  for (int i = t; i < NFIL * CLS; i += 256) sW2[i] = Wc2[i];
  if (t < NFIL) sb1[t] = bc1[t];
  __syncthreads();
  int r = t >> 4;
  int node = blockIdx.x * 16 + r;
  int f4 = t & 15;
  bool ok = node < n;
  int nd = ok ? node : 0;
  int cnt = ok ? grp_cnt[nd] : 0;
  const uint2* xw2 = reinterpret_cast<const uint2*>(xwb);
  float d = ok ? dinv[nd] : 0.f;
  uint2 g = xw2[(size_t)nd * 16 + f4];
  float4 acc = {d * __uint_as_float(g.x << 16),
                d * __uint_as_float(g.x & 0xFFFF0000u),
                d * __uint_as_float(g.y << 16),
                d * __uint_as_float(g.y & 0xFFFF0000u)};
  int p = 0;
  for (; p + 1 < cnt; p += 2) {
    uint v0 = slotc[(size_t)p * n + nd];
    uint v1 = slotc[(size_t)(p + 1) * n + nd];
    int s0 = v0 & 0x1FFFF, s1 = v1 & 0x1FFFF;
    float w0 = entw(v0) * dinv[s0];
    float w1 = entw(v1) * dinv[s1];
    uint2 g0 = xw2[(size_t)s0 * 16 + f4];
    uint2 g1 = xw2[(size_t)s1 * 16 + f4];
    acc.x = fmaf(w0, __uint_as_float(g0.x << 16), acc.x);
    acc.y = fmaf(w0, __uint_as_float(g0.x & 0xFFFF0000u), acc.y);
    acc.z = fmaf(w0, __uint_as_float(g0.y << 16), acc.z);
    acc.w = fmaf(w0, __uint_as_float(g0.y & 0xFFFF0000u), acc.w);
    acc.x = fmaf(w1, __uint_as_float(g1.x << 16), acc.x);
    acc.y = fmaf(w1, __uint_as_float(g1.x & 0xFFFF0000u), acc.y);
    acc.z = fmaf(w1, __uint_as_float(g1.y << 16), acc.z);
    acc.w = fmaf(w1, __uint_as_float(g1.y & 0xFFFF0000u), acc.w);
  }
  if (p < cnt) {
    uint v0 = slotc[(size_t)p * n + nd];
    int s0 = v0 & 0x1FFFF;
    float w0 = entw(v0) * dinv[s0];
    uint2 g0 = xw2[(size_t)s0 * 16 + f4];
    acc.x = fmaf(w0, __uint_as_float(g0.x << 16), acc.x);
    acc.y = fmaf(w0, __uint_as_float(g0.x & 0xFFFF0000u), acc.y);
    acc.z = fmaf(w0, __uint_as_float(g0.y << 16), acc.z);
    acc.w = fmaf(w0, __uint_as_float(g0.y & 0xFFFF0000u), acc.w);
  }
  sh[r][4*f4 + 0] = fmaxf(fmaf(d, acc.x, sb1[4*f4 + 0]), 0.f);
  sh[r][4*f4 + 1] = fmaxf(fmaf(d, acc.y, sb1[4*f4 + 1]), 0.f);
  sh[r][4*f4 + 2] = fmaxf(fmaf(d, acc.z, sb1[4*f4 + 2]), 0.f);
  sh[r][4*f4 + 3] = fmaxf(fmaf(d, acc.w, sb1[4*f4 + 3]), 0.f);
  __syncthreads();
  {
    int j = t & 15;
    float o = 0.f;
    #pragma unroll
    for (int k = 0; k < NFIL; k++) o = fmaf(sh[r][k], sW2[k * CLS + j], o);
    if (ok) ywb[(size_t)node * CLS + j] = (ushort)bf16_rn(o);
  }
}

// k5: agg layer 2 (register acc) + fused bc2 + log_softmax -> out
__global__ __launch_bounds__(256) void agg2_fused_kernel(
    const int* __restrict__ grp_cnt, const uint* __restrict__ slotc,
    const float* __restrict__ dinv, const ushort* __restrict__ ywb,
    const float* __restrict__ bc2, float* __restrict__ out, int n) {
  __shared__ float sb2[CLS];
  int t = threadIdx.x;
  if (t < CLS) sb2[t] = bc2[t];
  __syncthreads();
  int node = blockIdx.x * 16 + (t >> 4);
  int j = t & 15;
  bool ok = node < n;
  int nd = ok ? node : 0;
  int cnt = ok ? grp_cnt[nd] : 0;
  float d = ok ? dinv[nd] : 0.f;
  float acc = d * __uint_as_float((uint)ywb[(size_t)nd * CLS + j] << 16);
  int p = 0;
  for (; p + 1 < cnt; p += 2) {
    uint v0 = slotc[(size_t)p * n + nd];
    uint v1 = slotc[(size_t)(p + 1) * n + nd];
    int s0 = v0 & 0x1FFFF, s1 = v1 & 0x1FFFF;
    float w0 = entw(v0) * dinv[s0];
    float w1 = entw(v1) * dinv[s1];
    float y0 = __uint_as_float((uint)ywb[(size_t)s0 * CLS + j] << 16);
    float y1 = __uint_as_float((uint)ywb[(size_t)s1 * CLS + j] << 16);
    acc = fmaf(w0, y0, acc);
    acc = fmaf(w1, y1, acc);
  }
  if (p < cnt) {
    uint v0 = slotc[(size_t)p * n + nd];
    int s0 = v0 & 0x1FFFF;
    float w0 = entw(v0) * dinv[s0];
    acc = fmaf(w0, __uint_as_float((uint)ywb[(size_t)s0 * CLS + j] << 16), acc);
  }
  float v = fmaf(d, acc, sb2[j]);
  float m = v;
  m = fmaxf(m, __shfl_xor(m, 1, 16));
  m = fmaxf(m, __shfl_xor(m, 2, 16));
  m = fmaxf(m, __shfl_xor(m, 4, 16));
  m = fmaxf(m, __shfl_xor(m, 8, 16));
  float ex = __expf(v - m);
  float ssum = ex;
  ssum += __shfl_xor(ssum, 1, 16);
  ssum += __shfl_xor(ssum, 2, 16);
  ssum += __shfl_xor(ssum, 4, 16);
  ssum += __shfl_xor(ssum, 8, 16);
  if (ok) out[(size_t)node * CLS + j] = (v - m) - __logf(ssum);
}

extern "C" void kernel_launch(void* const* d_in, const int* in_sizes, int n_in,
                              void* d_out, int out_size, void* d_ws, size_t ws_size,
                              hipStream_t stream) {
  const float* x      = (const float*)d_in[0];
  const int*   ei     = (const int*)d_in[1];
  const float* edge_x = (const float*)d_in[2];
  const float* W1     = (const float*)d_in[3];
  const float* b1     = (const float*)d_in[4];
  const float* W2     = (const float*)d_in[5];
  const float* b2     = (const float*)d_in[6];
  const float* Wc1    = (const float*)d_in[7];
  const float* bc1    = (const float*)d_in[8];
  const float* Wc2    = (const float*)d_in[9];
  const float* bc2    = (const float*)d_in[10];
  float* outp = (float*)d_out;
  int n = in_sizes[0] / NFD;
  int E = in_sizes[1] / 2;

  // bytes = E*8 + n*(head32 + slot4*cap + cnt4 + dinv4 + xwb128 + ywb32)
  int cap = 48;
  while (cap > 32 && 8.0 * E + (double)n * (200.0 + 4.0 * cap) > (double)ws_size)
    cap -= 8;

  char* base = (char*)d_ws;
  int* head = (int*)base;            base += (size_t)n * 32;
  ull* nextbuf = (ull*)base;         base += (size_t)E * 8;
  uint* slotc = (uint*)base;         base += (size_t)n * cap * 4;
  int* grp_cnt = (int*)base;         base += (size_t)n * 4;
  float* dinv = (float*)base;        base += (size_t)n * 4;
  uint* xwb = (uint*)base;           base += (size_t)n * 128;
  ushort* ywb = (ushort*)base;

  int nblk16 = (n + 15) / 16;
  int nblk256 = (n + 255) / 256;
  hipMemsetAsync(head, 0xFF, (size_t)n * 32, stream);   // all heads = -1
  edge_mlp_link_kernel<<<(E + 255) / 256, 256, 0, stream>>>(
      edge_x, ei, W1, b1, W2, b2, head, nextbuf, E);
  walk_kernel<<<nblk256, 256, 0, stream>>>(head, nextbuf, slotc, grp_cnt, dinv, cap, n);
  gemm1_kernel<<<1024, 256, 0, stream>>>(x, Wc1, xwb, n);
  agg1_fused_kernel<<<nblk16, 256, 0, stream>>>(grp_cnt, slotc, dinv, xwb, bc1, Wc2, ywb, n);
  agg2_fused_kernel<<<nblk16, 256, 0, stream>>>(grp_cnt, slotc, dinv, ywb, bc2, outp, n);
}

// Round 9
// 230.476 us; speedup vs baseline: 1.0049x; 1.0049x over previous
//
#include <hip/hip_runtime.h>
#include <math.h>

#define NFD 128   // node features
#define EF_ 16    // edge features
#define EFIL 32   // edge MLP hidden
#define NFIL 64   // GCN layer-1 out
#define CLS 16    // classes

typedef unsigned int uint;
typedef unsigned long long ull;
typedef unsigned short ushort;

__device__ inline void fma4(float4& a, float s, const float4& w) {
  a.x = fmaf(s, w.x, a.x); a.y = fmaf(s, w.y, a.y);
  a.z = fmaf(s, w.z, a.z); a.w = fmaf(s, w.w, a.w);
}

// round-to-nearest-even bf16 bits of a finite float
__device__ inline uint bf16_rn(float f) {
  uint u = __float_as_uint(f);
  return (u + 0x7FFFu + ((u >> 16) & 1u)) >> 16;
}
__device__ inline float entw(uint lo) {          // decode (ew15<<17) -> float
  return __uint_as_float((lo >> 17) << 16);
}

// k1: edge MLP -> sigmoid weight; linked-list push into one of 8 replicated
// heads (exactly one 32B granule per node).  The atomicExch is issued BEFORE
// the MLP compute (it depends only on tgt), so its ~1us round-trip hides
// under ~600 VALU instructions of MLP work.  Payload store is coalesced.
__global__ __launch_bounds__(256) void edge_mlp_link_kernel(
    const float* __restrict__ edge_x, const int* __restrict__ ei,
    const float* __restrict__ W1, const float* __restrict__ b1,
    const float* __restrict__ W2, const float* __restrict__ b2,
    int* __restrict__ head, ull* __restrict__ nextbuf, int E) {
  __shared__ __align__(16) float sW1[EF_ * EFIL];  // [k][j] 16x32
  __shared__ float sb1[EFIL];
  __shared__ float sW2[EFIL];
  __shared__ float sb2v;
  int t = threadIdx.x;
  for (int idx = t; idx < EF_ * EFIL / 4; idx += 256)
    reinterpret_cast<float4*>(sW1)[idx] = reinterpret_cast<const float4*>(W1)[idx];
  if (t < EFIL) { sb1[t] = b1[t]; sW2[t] = W2[t]; }
  if (t == 64) sb2v = b2[0];
  __syncthreads();
  int e = blockIdx.x * 256 + t;
  if (e >= E) return;
  // --- issue the returning atomic FIRST (only needs tgt) ---
  int sv = ei[e], tg = ei[(size_t)E + e];
  int old = atomicExch(&head[(size_t)tg * 8 + (blockIdx.x & 7)], e);
  // --- MLP compute overlaps the atomic round-trip ---
  const float4* ex4 = reinterpret_cast<const float4*>(edge_x) + (size_t)e * (EF_ / 4);
  float ex[EF_];
  #pragma unroll
  for (int q = 0; q < EF_ / 4; q++) {
    float4 v = ex4[q];
    ex[4*q+0] = v.x; ex[4*q+1] = v.y; ex[4*q+2] = v.z; ex[4*q+3] = v.w;
  }
  float acc[EFIL];
  #pragma unroll
  for (int j = 0; j < EFIL; j++) acc[j] = sb1[j];
  #pragma unroll
  for (int k = 0; k < EF_; k++) {
    float xk = ex[k];
    #pragma unroll
    for (int j4 = 0; j4 < EFIL / 4; j4++) {
      float4 w = reinterpret_cast<const float4*>(sW1)[k * (EFIL/4) + j4];
      acc[4*j4+0] = fmaf(xk, w.x, acc[4*j4+0]);
      acc[4*j4+1] = fmaf(xk, w.y, acc[4*j4+1]);
      acc[4*j4+2] = fmaf(xk, w.z, acc[4*j4+2]);
      acc[4*j4+3] = fmaf(xk, w.w, acc[4*j4+3]);
    }
  }
  float s = sb2v;
  #pragma unroll
  for (int j = 0; j < EFIL; j++) s = fmaf(fmaxf(acc[j], 0.f), sW2[j], s);
  float sig = 1.0f / (1.0f + __expf(-s));
  uint lo = ((bf16_rn(sig) & 0x7FFFu) << 17) | (uint)sv;
  nextbuf[e] = ((ull)(uint)old << 32) | lo;
}

// k2: walk the 8 replica chains per node (interleaved -> 8 loads in flight,
// chain depth ~2 each), store entries COLUMN-MAJOR slot[p*n+i] (coalesced),
// per-node count + dinv = rsqrt(1 + sum ew).  1 thread per node.
__global__ __launch_bounds__(256) void walk_kernel(
    const int* __restrict__ head, const ull* __restrict__ nextbuf,
    uint* __restrict__ slotc, int* __restrict__ grp_cnt,
    float* __restrict__ dinv, int caprows, int n) {
  int i = blockIdx.x * blockDim.x + threadIdx.x;
  if (i >= n) return;
  int4 ha = *reinterpret_cast<const int4*>(head + (size_t)i * 8);
  int4 hb = *reinterpret_cast<const int4*>(head + (size_t)i * 8 + 4);
  int ev0 = ha.x, ev1 = ha.y, ev2 = ha.z, ev3 = ha.w;
  int ev4 = hb.x, ev5 = hb.y, ev6 = hb.z, ev7 = hb.w;
  int cnt = 0;
  float sum = 0.f;
  bool any = (ev0 | ev1 | ev2 | ev3 | ev4 | ev5 | ev6 | ev7) != -1 ||
             (ev0 >= 0 || ev1 >= 0 || ev2 >= 0 || ev3 >= 0 ||
              ev4 >= 0 || ev5 >= 0 || ev6 >= 0 || ev7 >= 0);
  while (any) {
    ull v0 = 0, v1 = 0, v2 = 0, v3 = 0, v4 = 0, v5 = 0, v6 = 0, v7 = 0;
    if (ev0 >= 0) v0 = nextbuf[ev0];
    if (ev1 >= 0) v1 = nextbuf[ev1];
    if (ev2 >= 0) v2 = nextbuf[ev2];
    if (ev3 >= 0) v3 = nextbuf[ev3];
    if (ev4 >= 0) v4 = nextbuf[ev4];
    if (ev5 >= 0) v5 = nextbuf[ev5];
    if (ev6 >= 0) v6 = nextbuf[ev6];
    if (ev7 >= 0) v7 = nextbuf[ev7];
    #define STEP(EV, VV)                                              \
    if (EV >= 0) {                                                    \
      uint lo = (uint)VV; sum += entw(lo);                            \
      if (cnt < caprows) slotc[(size_t)cnt * n + i] = lo;             \
      cnt++; EV = (int)(uint)(VV >> 32);                              \
    }
    STEP(ev0, v0) STEP(ev1, v1) STEP(ev2, v2) STEP(ev3, v3)
    STEP(ev4, v4) STEP(ev5, v5) STEP(ev6, v6) STEP(ev7, v7)
    #undef STEP
    any = ev0 >= 0 || ev1 >= 0 || ev2 >= 0 || ev3 >= 0 ||
          ev4 >= 0 || ev5 >= 0 || ev6 >= 0 || ev7 >= 0;
  }
  grp_cnt[i] = min(cnt, caprows);
  dinv[i] = rsqrtf(1.0f + sum);
}

// k3: xw = x @ Wc1, output bf16 (packed 2/uint, row = 32 uints)
__global__ __launch_bounds__(256) void gemm1_kernel(
    const float* __restrict__ x, const float* __restrict__ Wc1,
    uint* __restrict__ xwb, int n) {
  __shared__ __align__(16) float sW[NFD * NFIL];  // 32 KB, [k][c]
  int t = threadIdx.x;
  for (int idx = t; idx < NFD * NFIL / 4; idx += 256)
    reinterpret_cast<float4*>(sW)[idx] = reinterpret_cast<const float4*>(Wc1)[idx];
  __syncthreads();
  int tc = t & 15;
  int tr = t >> 4;
  int nrb = (n + 31) >> 5;
  const float4* sW4 = reinterpret_cast<const float4*>(sW);
  for (int rb = blockIdx.x; rb < nrb; rb += gridDim.x) {
    int r0 = rb * 32 + tr * 2;
    int r1 = r0 + 1;
    int c0 = r0 < n ? r0 : n - 1;
    int c1 = r1 < n ? r1 : n - 1;
    const float4* xr0 = reinterpret_cast<const float4*>(x + (size_t)c0 * NFD);
    const float4* xr1 = reinterpret_cast<const float4*>(x + (size_t)c1 * NFD);
    float4 a0 = {0, 0, 0, 0}, a1 = {0, 0, 0, 0};
    #pragma unroll 4
    for (int k4 = 0; k4 < NFD / 4; k4++) {
      float4 xa = xr0[k4];
      float4 xb = xr1[k4];
      float4 w0 = sW4[(k4*4+0)*16 + tc];
      float4 w1 = sW4[(k4*4+1)*16 + tc];
      float4 w2 = sW4[(k4*4+2)*16 + tc];
      float4 w3 = sW4[(k4*4+3)*16 + tc];
      fma4(a0, xa.x, w0); fma4(a0, xa.y, w1); fma4(a0, xa.z, w2); fma4(a0, xa.w, w3);
      fma4(a1, xb.x, w0); fma4(a1, xb.y, w1); fma4(a1, xb.z, w2); fma4(a1, xb.w, w3);
    }
    if (r0 < n) {
      uint2 o = {bf16_rn(a0.x) | (bf16_rn(a0.y) << 16),
                 bf16_rn(a0.z) | (bf16_rn(a0.w) << 16)};
      reinterpret_cast<uint2*>(xwb + (size_t)r0 * 32)[tc] = o;
    }
    if (r1 < n) {
      uint2 o = {bf16_rn(a1.x) | (bf16_rn(a1.y) << 16),
                 bf16_rn(a1.z) | (bf16_rn(a1.w) << 16)};
      reinterpret_cast<uint2*>(xwb + (size_t)r1 * 32)[tc] = o;
    }
  }
}

// k4: agg layer 1 (register acc, 16 lanes/node) + fused relu/bias + @Wc2 -> yw (bf16)
__global__ __launch_bounds__(256) void agg1_fused_kernel(
    const int* __restrict__ grp_cnt, const uint* __restrict__ slotc,
    const float* __restrict__ dinv, const uint* __restrict__ xwb,
    const float* __restrict__ bc1, const float* __restrict__ Wc2,
    ushort* __restrict__ ywb, int n) {
  __shared__ float sh[16][NFIL + 4];   // 4.4 KB
  __shared__ float sW2[NFIL * CLS];    // 4 KB
  __shared__ float sb1[NFIL];
  int t = threadIdx.x;
  for (int i = t; i < NFIL * CLS; i += 256) sW2[i] = Wc2[i];
  if (t < NFIL) sb1[t] = bc1[t];
  __syncthreads();
  int r = t >> 4;
  int node = blockIdx.x * 16 + r;
  int f4 = t & 15;
  bool ok = node < n;
  int nd = ok ? node : 0;
  int cnt = ok ? grp_cnt[nd] : 0;
  const uint2* xw2 = reinterpret_cast<const uint2*>(xwb);
  float d = ok ? dinv[nd] : 0.f;
  uint2 g = xw2[(size_t)nd * 16 + f4];
  float4 acc = {d * __uint_as_float(g.x << 16),
                d * __uint_as_float(g.x & 0xFFFF0000u),
                d * __uint_as_float(g.y << 16),
                d * __uint_as_float(g.y & 0xFFFF0000u)};
  int p = 0;
  for (; p + 1 < cnt; p += 2) {
    uint v0 = slotc[(size_t)p * n + nd];
    uint v1 = slotc[(size_t)(p + 1) * n + nd];
    int s0 = v0 & 0x1FFFF, s1 = v1 & 0x1FFFF;
    float w0 = entw(v0) * dinv[s0];
    float w1 = entw(v1) * dinv[s1];
    uint2 g0 = xw2[(size_t)s0 * 16 + f4];
    uint2 g1 = xw2[(size_t)s1 * 16 + f4];
    acc.x = fmaf(w0, __uint_as_float(g0.x << 16), acc.x);
    acc.y = fmaf(w0, __uint_as_float(g0.x & 0xFFFF0000u), acc.y);
    acc.z = fmaf(w0, __uint_as_float(g0.y << 16), acc.z);
    acc.w = fmaf(w0, __uint_as_float(g0.y & 0xFFFF0000u), acc.w);
    acc.x = fmaf(w1, __uint_as_float(g1.x << 16), acc.x);
    acc.y = fmaf(w1, __uint_as_float(g1.x & 0xFFFF0000u), acc.y);
    acc.z = fmaf(w1, __uint_as_float(g1.y << 16), acc.z);
    acc.w = fmaf(w1, __uint_as_float(g1.y & 0xFFFF0000u), acc.w);
  }
  if (p < cnt) {
    uint v0 = slotc[(size_t)p * n + nd];
    int s0 = v0 & 0x1FFFF;
    float w0 = entw(v0) * dinv[s0];
    uint2 g0 = xw2[(size_t)s0 * 16 + f4];
    acc.x = fmaf(w0, __uint_as_float(g0.x << 16), acc.x);
    acc.y = fmaf(w0, __uint_as_float(g0.x & 0xFFFF0000u), acc.y);
    acc.z = fmaf(w0, __uint_as_float(g0.y << 16), acc.z);
    acc.w = fmaf(w0, __uint_as_float(g0.y & 0xFFFF0000u), acc.w);
  }
  sh[r][4*f4 + 0] = fmaxf(fmaf(d, acc.x, sb1[4*f4 + 0]), 0.f);
  sh[r][4*f4 + 1] = fmaxf(fmaf(d, acc.y, sb1[4*f4 + 1]), 0.f);
  sh[r][4*f4 + 2] = fmaxf(fmaf(d, acc.z, sb1[4*f4 + 2]), 0.f);
  sh[r][4*f4 + 3] = fmaxf(fmaf(d, acc.w, sb1[4*f4 + 3]), 0.f);
  __syncthreads();
  {
    int j = t & 15;
    float o = 0.f;
    #pragma unroll
    for (int k = 0; k < NFIL; k++) o = fmaf(sh[r][k], sW2[k * CLS + j], o);
    if (ok) ywb[(size_t)node * CLS + j] = (ushort)bf16_rn(o);
  }
}

// k5: agg layer 2 (register acc) + fused bc2 + log_softmax -> out
__global__ __launch_bounds__(256) void agg2_fused_kernel(
    const int* __restrict__ grp_cnt, const uint* __restrict__ slotc,
    const float* __restrict__ dinv, const ushort* __restrict__ ywb,
    const float* __restrict__ bc2, float* __restrict__ out, int n) {
  __shared__ float sb2[CLS];
  int t = threadIdx.x;
  if (t < CLS) sb2[t] = bc2[t];
  __syncthreads();
  int node = blockIdx.x * 16 + (t >> 4);
  int j = t & 15;
  bool ok = node < n;
  int nd = ok ? node : 0;
  int cnt = ok ? grp_cnt[nd] : 0;
  float d = ok ? dinv[nd] : 0.f;
  float acc = d * __uint_as_float((uint)ywb[(size_t)nd * CLS + j] << 16);
  int p = 0;
  for (; p + 1 < cnt; p += 2) {
    uint v0 = slotc[(size_t)p * n + nd];
    uint v1 = slotc[(size_t)(p + 1) * n + nd];
    int s0 = v0 & 0x1FFFF, s1 = v1 & 0x1FFFF;
    float w0 = entw(v0) * dinv[s0];
    float w1 = entw(v1) * dinv[s1];
    float y0 = __uint_as_float((uint)ywb[(size_t)s0 * CLS + j] << 16);
    float y1 = __uint_as_float((uint)ywb[(size_t)s1 * CLS + j] << 16);
    acc = fmaf(w0, y0, acc);
    acc = fmaf(w1, y1, acc);
  }
  if (p < cnt) {
    uint v0 = slotc[(size_t)p * n + nd];
    int s0 = v0 & 0x1FFFF;
    float w0 = entw(v0) * dinv[s0];
    acc = fmaf(w0, __uint_as_float((uint)ywb[(size_t)s0 * CLS + j] << 16), acc);
  }
  float v = fmaf(d, acc, sb2[j]);
  float m = v;
  m = fmaxf(m, __shfl_xor(m, 1, 16));
  m = fmaxf(m, __shfl_xor(m, 2, 16));
  m = fmaxf(m, __shfl_xor(m, 4, 16));
  m = fmaxf(m, __shfl_xor(m, 8, 16));
  float ex = __expf(v - m);
  float ssum = ex;
  ssum += __shfl_xor(ssum, 1, 16);
  ssum += __shfl_xor(ssum, 2, 16);
  ssum += __shfl_xor(ssum, 4, 16);
  ssum += __shfl_xor(ssum, 8, 16);
  if (ok) out[(size_t)node * CLS + j] = (v - m) - __logf(ssum);
}

extern "C" void kernel_launch(void* const* d_in, const int* in_sizes, int n_in,
                              void* d_out, int out_size, void* d_ws, size_t ws_size,
                              hipStream_t stream) {
  const float* x      = (const float*)d_in[0];
  const int*   ei     = (const int*)d_in[1];
  const float* edge_x = (const float*)d_in[2];
  const float* W1     = (const float*)d_in[3];
  const float* b1     = (const float*)d_in[4];
  const float* W2     = (const float*)d_in[5];
  const float* b2     = (const float*)d_in[6];
  const float* Wc1    = (const float*)d_in[7];
  const float* bc1    = (const float*)d_in[8];
  const float* Wc2    = (const float*)d_in[9];
  const float* bc2    = (const float*)d_in[10];
  float* outp = (float*)d_out;
  int n = in_sizes[0] / NFD;
  int E = in_sizes[1] / 2;

  // bytes = E*8 + n*(head32 + slot4*cap + cnt4 + dinv4 + xwb128 + ywb32)
  int cap = 48;
  while (cap > 32 && 8.0 * E + (double)n * (200.0 + 4.0 * cap) > (double)ws_size)
    cap -= 8;

  char* base = (char*)d_ws;
  int* head = (int*)base;            base += (size_t)n * 32;
  ull* nextbuf = (ull*)base;         base += (size_t)E * 8;
  uint* slotc = (uint*)base;         base += (size_t)n * cap * 4;
  int* grp_cnt = (int*)base;         base += (size_t)n * 4;
  float* dinv = (float*)base;        base += (size_t)n * 4;
  uint* xwb = (uint*)base;           base += (size_t)n * 128;
  ushort* ywb = (ushort*)base;

  int nblk16 = (n + 15) / 16;
  int nblk256 = (n + 255) / 256;
  hipMemsetAsync(head, 0xFF, (size_t)n * 32, stream);   // all 8 heads = -1
  edge_mlp_link_kernel<<<(E + 255) / 256, 256, 0, stream>>>(
      edge_x, ei, W1, b1, W2, b2, head, nextbuf, E);
  walk_kernel<<<nblk256, 256, 0, stream>>>(head, nextbuf, slotc, grp_cnt, dinv, cap, n);
  gemm1_kernel<<<1024, 256, 0, stream>>>(x, Wc1, xwb, n);
  agg1_fused_kernel<<<nblk16, 256, 0, stream>>>(grp_cnt, slotc, dinv, xwb, bc1, Wc2, ywb, n);
  agg2_fused_kernel<<<nblk16, 256, 0, stream>>>(grp_cnt, slotc, dinv, ywb, bc2, outp, n);
}

// Round 10
// 195.317 us; speedup vs baseline: 1.1858x; 1.1800x over previous
//
#include <hip/hip_runtime.h>
#include <math.h>

#define NFD 128   // node features
#define EF_ 16    // edge features
#define EFIL 32   // edge MLP hidden
#define NFIL 64   // GCN layer-1 out
#define CLS 16    // classes

typedef unsigned int uint;
typedef unsigned long long ull;
typedef unsigned short ushort;

__device__ inline void fma4(float4& a, float s, const float4& w) {
  a.x = fmaf(s, w.x, a.x); a.y = fmaf(s, w.y, a.y);
  a.z = fmaf(s, w.z, a.z); a.w = fmaf(s, w.w, a.w);
}

// round-to-nearest-even bf16 bits of a finite float
__device__ inline uint bf16_rn(float f) {
  uint u = __float_as_uint(f);
  return (u + 0x7FFFu + ((u >> 16) & 1u)) >> 16;
}
__device__ inline float entw(uint lo) {          // decode (ew15<<17) -> float
  return __uint_as_float((lo >> 17) << 16);
}

// k1 (fused): interleaved edge-MLP blocks and gemm1 blocks.
// Block role: (bid+1)%7==0 -> gemm (gidx=(bid+1)/7-1, grid-stride NBG);
// else edge (eidx = bid - (bid+1)/7).  gemm blocks co-reside with edge
// blocks and their dense FMA work fills the edge blocks' atomic-wait bubbles.
__global__ __launch_bounds__(256) void edge_gemm_kernel(
    const float* __restrict__ edge_x, const int* __restrict__ ei,
    const float* __restrict__ W1, const float* __restrict__ b1,
    const float* __restrict__ W2, const float* __restrict__ b2,
    int* __restrict__ head, ull* __restrict__ nextbuf, int E,
    const float* __restrict__ x, const float* __restrict__ Wc1,
    uint* __restrict__ xwb, int n, int NBG) {
  extern __shared__ __align__(16) char smem[];
  int t = threadIdx.x;
  int bid = blockIdx.x;
  int gq = (bid + 1) / 7;
  bool is_gemm = ((bid + 1) % 7) == 0;

  if (is_gemm) {
    // ---------------- gemm1: xw = x @ Wc1 -> bf16 ----------------
    float* sW = (float*)smem;                      // 32 KB, [k][c]
    for (int idx = t; idx < NFD * NFIL / 4; idx += 256)
      reinterpret_cast<float4*>(sW)[idx] = reinterpret_cast<const float4*>(Wc1)[idx];
    __syncthreads();
    int tc = t & 15;
    int tr = t >> 4;
    int nrb = (n + 31) >> 5;
    const float4* sW4 = reinterpret_cast<const float4*>(sW);
    for (int rb = gq - 1; rb < nrb; rb += NBG) {
      int r0 = rb * 32 + tr * 2;
      int r1 = r0 + 1;
      int c0 = r0 < n ? r0 : n - 1;
      int c1 = r1 < n ? r1 : n - 1;
      const float4* xr0 = reinterpret_cast<const float4*>(x + (size_t)c0 * NFD);
      const float4* xr1 = reinterpret_cast<const float4*>(x + (size_t)c1 * NFD);
      float4 a0 = {0, 0, 0, 0}, a1 = {0, 0, 0, 0};
      #pragma unroll 4
      for (int k4 = 0; k4 < NFD / 4; k4++) {
        float4 xa = xr0[k4];
        float4 xb = xr1[k4];
        float4 w0 = sW4[(k4*4+0)*16 + tc];
        float4 w1 = sW4[(k4*4+1)*16 + tc];
        float4 w2 = sW4[(k4*4+2)*16 + tc];
        float4 w3 = sW4[(k4*4+3)*16 + tc];
        fma4(a0, xa.x, w0); fma4(a0, xa.y, w1); fma4(a0, xa.z, w2); fma4(a0, xa.w, w3);
        fma4(a1, xb.x, w0); fma4(a1, xb.y, w1); fma4(a1, xb.z, w2); fma4(a1, xb.w, w3);
      }
      if (r0 < n) {
        uint2 o = {bf16_rn(a0.x) | (bf16_rn(a0.y) << 16),
                   bf16_rn(a0.z) | (bf16_rn(a0.w) << 16)};
        reinterpret_cast<uint2*>(xwb + (size_t)r0 * 32)[tc] = o;
      }
      if (r1 < n) {
        uint2 o = {bf16_rn(a1.x) | (bf16_rn(a1.y) << 16),
                   bf16_rn(a1.z) | (bf16_rn(a1.w) << 16)};
        reinterpret_cast<uint2*>(xwb + (size_t)r1 * 32)[tc] = o;
      }
    }
    return;
  }

  // ---------------- edge MLP + linked-list push ----------------
  int eidx = bid - gq;
  float* sW1 = (float*)smem;            // 16x32
  float* sb1 = sW1 + EF_ * EFIL;
  float* sW2 = sb1 + EFIL;
  float* sb2 = sW2 + EFIL;
  for (int idx = t; idx < EF_ * EFIL / 4; idx += 256)
    reinterpret_cast<float4*>(sW1)[idx] = reinterpret_cast<const float4*>(W1)[idx];
  if (t < EFIL) { sb1[t] = b1[t]; sW2[t] = W2[t]; }
  if (t == 64) sb2[0] = b2[0];
  __syncthreads();
  int e = eidx * 256 + t;
  if (e >= E) return;
  // issue the returning atomic FIRST (only needs tgt)
  int sv = ei[e], tg = ei[(size_t)E + e];
  int old = atomicExch(&head[(size_t)tg * 8 + (eidx & 7)], e);
  // MLP compute overlaps the atomic round-trip
  const float4* ex4 = reinterpret_cast<const float4*>(edge_x) + (size_t)e * (EF_ / 4);
  float ex[EF_];
  #pragma unroll
  for (int q = 0; q < EF_ / 4; q++) {
    float4 v = ex4[q];
    ex[4*q+0] = v.x; ex[4*q+1] = v.y; ex[4*q+2] = v.z; ex[4*q+3] = v.w;
  }
  float acc[EFIL];
  #pragma unroll
  for (int j = 0; j < EFIL; j++) acc[j] = sb1[j];
  #pragma unroll
  for (int k = 0; k < EF_; k++) {
    float xk = ex[k];
    #pragma unroll
    for (int j4 = 0; j4 < EFIL / 4; j4++) {
      float4 w = reinterpret_cast<const float4*>(sW1)[k * (EFIL/4) + j4];
      acc[4*j4+0] = fmaf(xk, w.x, acc[4*j4+0]);
      acc[4*j4+1] = fmaf(xk, w.y, acc[4*j4+1]);
      acc[4*j4+2] = fmaf(xk, w.z, acc[4*j4+2]);
      acc[4*j4+3] = fmaf(xk, w.w, acc[4*j4+3]);
    }
  }
  float s = sb2[0];
  #pragma unroll
  for (int j = 0; j < EFIL; j++) s = fmaf(fmaxf(acc[j], 0.f), sW2[j], s);
  float sig = 1.0f / (1.0f + __expf(-s));
  uint lo = ((bf16_rn(sig) & 0x7FFFu) << 17) | (uint)sv;
  nextbuf[e] = ((ull)(uint)old << 32) | lo;
}

// k2: walk the 8 replica chains per node (interleaved -> 8 loads in flight),
// store entries COLUMN-MAJOR slot[p*n+i], per-node count + dinv.
__global__ __launch_bounds__(256) void walk_kernel(
    const int* __restrict__ head, const ull* __restrict__ nextbuf,
    uint* __restrict__ slotc, int* __restrict__ grp_cnt,
    float* __restrict__ dinv, int caprows, int n) {
  int i = blockIdx.x * blockDim.x + threadIdx.x;
  if (i >= n) return;
  int4 ha = *reinterpret_cast<const int4*>(head + (size_t)i * 8);
  int4 hb = *reinterpret_cast<const int4*>(head + (size_t)i * 8 + 4);
  int ev0 = ha.x, ev1 = ha.y, ev2 = ha.z, ev3 = ha.w;
  int ev4 = hb.x, ev5 = hb.y, ev6 = hb.z, ev7 = hb.w;
  int cnt = 0;
  float sum = 0.f;
  bool any = ev0 >= 0 || ev1 >= 0 || ev2 >= 0 || ev3 >= 0 ||
             ev4 >= 0 || ev5 >= 0 || ev6 >= 0 || ev7 >= 0;
  while (any) {
    ull v0 = 0, v1 = 0, v2 = 0, v3 = 0, v4 = 0, v5 = 0, v6 = 0, v7 = 0;
    if (ev0 >= 0) v0 = nextbuf[ev0];
    if (ev1 >= 0) v1 = nextbuf[ev1];
    if (ev2 >= 0) v2 = nextbuf[ev2];
    if (ev3 >= 0) v3 = nextbuf[ev3];
    if (ev4 >= 0) v4 = nextbuf[ev4];
    if (ev5 >= 0) v5 = nextbuf[ev5];
    if (ev6 >= 0) v6 = nextbuf[ev6];
    if (ev7 >= 0) v7 = nextbuf[ev7];
    #define STEP(EV, VV)                                              \
    if (EV >= 0) {                                                    \
      uint lo = (uint)VV; sum += entw(lo);                            \
      if (cnt < caprows) slotc[(size_t)cnt * n + i] = lo;             \
      cnt++; EV = (int)(uint)(VV >> 32);                              \
    }
    STEP(ev0, v0) STEP(ev1, v1) STEP(ev2, v2) STEP(ev3, v3)
    STEP(ev4, v4) STEP(ev5, v5) STEP(ev6, v6) STEP(ev7, v7)
    #undef STEP
    any = ev0 >= 0 || ev1 >= 0 || ev2 >= 0 || ev3 >= 0 ||
          ev4 >= 0 || ev5 >= 0 || ev6 >= 0 || ev7 >= 0;
  }
  grp_cnt[i] = min(cnt, caprows);
  dinv[i] = rsqrtf(1.0f + sum);
}

// k4: agg layer 1 (register acc, 16 lanes/node, 4-deep unroll) + fused
// relu/bias + @Wc2 -> ywb premultiplied by dinv[node] (bf16)
__global__ __launch_bounds__(256) void agg1_fused_kernel(
    const int* __restrict__ grp_cnt, const uint* __restrict__ slotc,
    const float* __restrict__ dinv, const uint* __restrict__ xwb,
    const float* __restrict__ bc1, const float* __restrict__ Wc2,
    ushort* __restrict__ ywb, int n) {
  __shared__ float sh[16][NFIL + 4];   // 4.4 KB
  __shared__ float sW2[NFIL * CLS];    // 4 KB
  __shared__ float sb1[NFIL];
  int t = threadIdx.x;
  for (int i = t; i < NFIL * CLS; i += 256) sW2[i] = Wc2[i];
  if (t < NFIL) sb1[t] = bc1[t];
  __syncthreads();
  int r = t >> 4;
  int node = blockIdx.x * 16 + r;
  int f4 = t & 15;
  bool ok = node < n;
  int nd = ok ? node : 0;
  int cnt = ok ? grp_cnt[nd] : 0;
  const uint2* xw2 = reinterpret_cast<const uint2*>(xwb);
  float d = ok ? dinv[nd] : 0.f;
  uint2 g = xw2[(size_t)nd * 16 + f4];
  float4 acc = {d * __uint_as_float(g.x << 16),
                d * __uint_as_float(g.x & 0xFFFF0000u),
                d * __uint_as_float(g.y << 16),
                d * __uint_as_float(g.y & 0xFFFF0000u)};
  #define A1STEP(VV)                                                  \
  {                                                                   \
    int s_ = VV & 0x1FFFF;                                            \
    float w_ = entw(VV) * dinv[s_];                                   \
    uint2 g_ = xw2[(size_t)s_ * 16 + f4];                             \
    acc.x = fmaf(w_, __uint_as_float(g_.x << 16), acc.x);             \
    acc.y = fmaf(w_, __uint_as_float(g_.x & 0xFFFF0000u), acc.y);     \
    acc.z = fmaf(w_, __uint_as_float(g_.y << 16), acc.z);             \
    acc.w = fmaf(w_, __uint_as_float(g_.y & 0xFFFF0000u), acc.w);     \
  }
  int p = 0;
  for (; p + 3 < cnt; p += 4) {
    uint v0 = slotc[(size_t)p * n + nd];
    uint v1 = slotc[(size_t)(p + 1) * n + nd];
    uint v2 = slotc[(size_t)(p + 2) * n + nd];
    uint v3 = slotc[(size_t)(p + 3) * n + nd];
    A1STEP(v0) A1STEP(v1) A1STEP(v2) A1STEP(v3)
  }
  for (; p < cnt; p++) {
    uint v0 = slotc[(size_t)p * n + nd];
    A1STEP(v0)
  }
  #undef A1STEP
  sh[r][4*f4 + 0] = fmaxf(fmaf(d, acc.x, sb1[4*f4 + 0]), 0.f);
  sh[r][4*f4 + 1] = fmaxf(fmaf(d, acc.y, sb1[4*f4 + 1]), 0.f);
  sh[r][4*f4 + 2] = fmaxf(fmaf(d, acc.z, sb1[4*f4 + 2]), 0.f);
  sh[r][4*f4 + 3] = fmaxf(fmaf(d, acc.w, sb1[4*f4 + 3]), 0.f);
  __syncthreads();
  {
    int j = t & 15;
    float o = 0.f;
    #pragma unroll
    for (int k = 0; k < NFIL; k++) o = fmaf(sh[r][k], sW2[k * CLS + j], o);
    if (ok) ywb[(size_t)node * CLS + j] = (ushort)bf16_rn(d * o);  // premult by d
  }
}

// k5: agg layer 2 (register acc, 4-deep unroll; ywb premultiplied so no
// dinv[src] gather) + fused bc2 + log_softmax -> out
__global__ __launch_bounds__(256) void agg2_fused_kernel(
    const int* __restrict__ grp_cnt, const uint* __restrict__ slotc,
    const float* __restrict__ dinv, const ushort* __restrict__ ywb,
    const float* __restrict__ bc2, float* __restrict__ out, int n) {
  __shared__ float sb2[CLS];
  int t = threadIdx.x;
  if (t < CLS) sb2[t] = bc2[t];
  __syncthreads();
  int node = blockIdx.x * 16 + (t >> 4);
  int j = t & 15;
  bool ok = node < n;
  int nd = ok ? node : 0;
  int cnt = ok ? grp_cnt[nd] : 0;
  float d = ok ? dinv[nd] : 0.f;
  // ywb already holds dinv[i]*yw[i]; self term: d_i*yw_i contribution is
  // ywb[i] itself inside the bracket.
  float acc = __uint_as_float((uint)ywb[(size_t)nd * CLS + j] << 16);
  #define A2STEP(VV)                                                       \
  {                                                                        \
    int s_ = VV & 0x1FFFF;                                                 \
    acc = fmaf(entw(VV),                                                   \
               __uint_as_float((uint)ywb[(size_t)s_ * CLS + j] << 16),     \
               acc);                                                       \
  }
  int p = 0;
  for (; p + 3 < cnt; p += 4) {
    uint v0 = slotc[(size_t)p * n + nd];
    uint v1 = slotc[(size_t)(p + 1) * n + nd];
    uint v2 = slotc[(size_t)(p + 2) * n + nd];
    uint v3 = slotc[(size_t)(p + 3) * n + nd];
    A2STEP(v0) A2STEP(v1) A2STEP(v2) A2STEP(v3)
  }
  for (; p < cnt; p++) {
    uint v0 = slotc[(size_t)p * n + nd];
    A2STEP(v0)
  }
  #undef A2STEP
  float v = fmaf(d, acc, sb2[j]);
  float m = v;
  m = fmaxf(m, __shfl_xor(m, 1, 16));
  m = fmaxf(m, __shfl_xor(m, 2, 16));
  m = fmaxf(m, __shfl_xor(m, 4, 16));
  m = fmaxf(m, __shfl_xor(m, 8, 16));
  float ex = __expf(v - m);
  float ssum = ex;
  ssum += __shfl_xor(ssum, 1, 16);
  ssum += __shfl_xor(ssum, 2, 16);
  ssum += __shfl_xor(ssum, 4, 16);
  ssum += __shfl_xor(ssum, 8, 16);
  if (ok) out[(size_t)node * CLS + j] = (v - m) - __logf(ssum);
}

extern "C" void kernel_launch(void* const* d_in, const int* in_sizes, int n_in,
                              void* d_out, int out_size, void* d_ws, size_t ws_size,
                              hipStream_t stream) {
  const float* x      = (const float*)d_in[0];
  const int*   ei     = (const int*)d_in[1];
  const float* edge_x = (const float*)d_in[2];
  const float* W1     = (const float*)d_in[3];
  const float* b1     = (const float*)d_in[4];
  const float* W2     = (const float*)d_in[5];
  const float* b2     = (const float*)d_in[6];
  const float* Wc1    = (const float*)d_in[7];
  const float* bc1    = (const float*)d_in[8];
  const float* Wc2    = (const float*)d_in[9];
  const float* bc2    = (const float*)d_in[10];
  float* outp = (float*)d_out;
  int n = in_sizes[0] / NFD;
  int E = in_sizes[1] / 2;

  // bytes = E*8 + n*(head32 + slot4*cap + cnt4 + dinv4 + xwb128 + ywb32)
  int cap = 48;
  while (cap > 32 && 8.0 * E + (double)n * (200.0 + 4.0 * cap) > (double)ws_size)
    cap -= 8;

  char* base = (char*)d_ws;
  int* head = (int*)base;            base += (size_t)n * 32;
  ull* nextbuf = (ull*)base;         base += (size_t)E * 8;
  uint* slotc = (uint*)base;         base += (size_t)n * cap * 4;
  int* grp_cnt = (int*)base;         base += (size_t)n * 4;
  float* dinv = (float*)base;        base += (size_t)n * 4;
  uint* xwb = (uint*)base;           base += (size_t)n * 128;
  ushort* ywb = (ushort*)base;

  // fused grid: every 7th block is a gemm block.
  int NBE = (E + 255) / 256;                 // edge blocks needed
  // total T with T - floor(T/7) == NBE  ->  T = NBE + floor(T/7)
  int T = NBE;
  for (int it = 0; it < 8; it++) T = NBE + T / 7;
  while (T - T / 7 < NBE) T++;
  int NBG = T / 7;                           // gemm blocks (grid-stride)

  int nblk16 = (n + 15) / 16;
  int nblk256 = (n + 255) / 256;
  hipMemsetAsync(head, 0xFF, (size_t)n * 32, stream);   // all 8 heads = -1
  edge_gemm_kernel<<<T, 256, 32768, stream>>>(
      edge_x, ei, W1, b1, W2, b2, head, nextbuf, E, x, Wc1, xwb, n, NBG);
  walk_kernel<<<nblk256, 256, 0, stream>>>(head, nextbuf, slotc, grp_cnt, dinv, cap, n);
  agg1_fused_kernel<<<nblk16, 256, 0, stream>>>(grp_cnt, slotc, dinv, xwb, bc1, Wc2, ywb, n);
  agg2_fused_kernel<<<nblk16, 256, 0, stream>>>(grp_cnt, slotc, dinv, ywb, bc2, outp, n);
}